// Round 12
// baseline (402.458 us; speedup 1.0000x reference)
//
#include <hip/hip_runtime.h>
#include <stdint.h>

typedef __bf16 bf16;
typedef __bf16 bf16x8 __attribute__((ext_vector_type(8)));
typedef __bf16 bf16x4 __attribute__((ext_vector_type(4)));
typedef float  f32x4  __attribute__((ext_vector_type(4)));
typedef float  f32x16 __attribute__((ext_vector_type(16)));
typedef float  float4v __attribute__((ext_vector_type(4)));
typedef int    int4v   __attribute__((ext_vector_type(4)));
typedef unsigned int uint;

// log2(e)/sqrt(32): folds softmax 1/sqrt(Dh) and e^x -> 2^x into Q scaling
#define QSCALE 0.25505003984214403f

// Fragment-native layout: [bh][blk(128)][sub(4)][lane(32)][8]
//  Q/K: (pos,d) -> blk=pos>>5, sub=d>>3, lane=pos&31, j=d&7
//  V  : (key,d) -> blk=key>>5, sub from key5 bits{4,2}, lane=d, j=g*4+(key5&3), g=(key5>>3)&1
// Mask M2: dword [(b*128+kdw)*4096 + q], bit k5 of kdw*32+k5 vs q.

// ---------------- K0: transpose weights -> bf16 WT[w][n][k] ----------------
__global__ __launch_bounds__(256) void transpose_w(
    const float* __restrict__ w0, const float* __restrict__ w1,
    const float* __restrict__ w2, const float* __restrict__ w3,
    bf16* __restrict__ WT) {
  const int wsel = blockIdx.z;
  const float* W = wsel == 0 ? w0 : wsel == 1 ? w1 : wsel == 2 ? w2 : w3;
  const int k0 = blockIdx.x * 64, n0 = blockIdx.y * 64;
  __shared__ __align__(16) bf16 t[64][72];
  const int tid = threadIdx.x;
  {
    const int kk = (tid >> 4) << 2;
    const int nn = (tid & 15) << 2;
#pragma unroll
    for (int r = 0; r < 4; ++r) {
      float4v a = *(const float4v*)(W + (size_t)(k0 + kk + r) * 256 + n0 + nn);
#pragma unroll
      for (int j = 0; j < 4; ++j) t[nn + j][kk + r] = (bf16)a[j];
    }
  }
  __syncthreads();
  {
    const int ni = tid >> 2;
    const int c  = (tid & 3) * 16;
    bf16x8 o0 = *(const bf16x8*)(&t[ni][c]);
    bf16x8 o1 = *(const bf16x8*)(&t[ni][c + 8]);
    bf16* dst = WT + (size_t)wsel * 65536 + (size_t)(n0 + ni) * 256 + k0 + c;
    *(bf16x8*)dst = o0;
    *(bf16x8*)(dst + 8) = o1;
  }
}

// ---------------- K1: fused proj (blocks 0..767) + pack_mask (768..1279) ----
// FROZEN: 5 structural variants all land at 77-79us (coalescing, ILP depth,
// split/fused, register budget). The mask read stream runs at ~1.4 TB/s on
// this machine regardless — treated as a platform ceiling for this pattern.
__global__ __launch_bounds__(256)
__attribute__((amdgpu_waves_per_eu(4, 4)))
void proj_pack(
    const float* __restrict__ xq, const float* __restrict__ xk, const float* __restrict__ xv,
    const bf16* __restrict__ WT,
    bf16* __restrict__ Qp, bf16* __restrict__ Kp, bf16* __restrict__ Vp,
    const int* __restrict__ mask, uint* __restrict__ M2) {
  __shared__ __align__(16) unsigned char smem[18432];
  const int tid = threadIdx.x;

  if (blockIdx.x >= 768) {
    // ---- pack_mask: 64 q x 1024 k tile, fully-coalesced reads ----
    uint* lds32 = (uint*)smem;                    // [64][65] u32, pitch 65 (conflict-free)
    const int pid = blockIdx.x - 768;             // 512 blocks
    const int bb = pid >> 8;                      // batch
    const int qt = (pid >> 2) & 63, kc = pid & 3;
    const int q0 = qt * 64;
    const int w = tid >> 6, l = tid & 63;
#pragma unroll 4
    for (int r = 0; r < 16; ++r) {
      const int row = w * 16 + r;
      const size_t rowbase = ((size_t)(bb * 4096 + q0 + row)) * 4096 + kc * 1024;
      uint u = 0;
#pragma unroll
      for (int i = 0; i < 4; ++i) {
        int4v m = *(const int4v*)(mask + rowbase + i * 256 + l * 4);
        uint nib = (m[0] != 0 ? 1u : 0u) | (m[1] != 0 ? 2u : 0u) |
                   (m[2] != 0 ? 4u : 0u) | (m[3] != 0 ? 8u : 0u);
        u |= nib << (i * 8);
      }
      lds32[row * 65 + l] = u;
    }
    __syncthreads();
    {
      const int q = tid & 63, kg = tid >> 6;
      const uint* lrow = lds32 + q * 65;
      const int sh = kg * 8;
      uint* o = M2 + ((size_t)(bb * 128 + kc * 32 + kg * 8)) * 4096 + q0 + q;
#pragma unroll
      for (int j = 0; j < 8; ++j) {
        uint d = 0;
#pragma unroll
        for (int jj = 0; jj < 8; ++jj) {
          const uint wv = lrow[j * 8 + jj];
          d |= ((wv >> sh) & 0xFu) << (jj * 4);
        }
        o[(size_t)j * 4096] = d;
      }
    }
    return;
  }

  // ---- proj: 64 pos x 128 cols tile, epilogue through LDS for coalesced stores ----
  const int z = blockIdx.x >> 8;
  const int r8 = blockIdx.x & 255;
  const int m0 = (r8 >> 1) * 64, n0 = (r8 & 1) * 128;
  const float* X = z == 0 ? xq : (z == 1 ? xk : xv);
  const bf16* wt = WT + (size_t)z * 65536;
  const int wave = tid >> 6, lane = tid & 63;
  const int nl = lane & 15, quad = lane >> 4;
  const int arow = m0 + wave * 16 + nl;
  const float* xrow = X + (size_t)arow * 256;

  f32x4 zero4 = {0.f, 0.f, 0.f, 0.f};
  f32x4 acc[8];
#pragma unroll
  for (int i = 0; i < 8; ++i) acc[i] = zero4;

#pragma unroll
  for (int ks = 0; ks < 8; ++ks) {
    float4v a0 = *(const float4v*)(xrow + ks * 32 + quad * 8);
    float4v a1 = *(const float4v*)(xrow + ks * 32 + quad * 8 + 4);
    bf16x8 af;
#pragma unroll
    for (int i = 0; i < 4; ++i) { af[i] = (bf16)a0[i]; af[4 + i] = (bf16)a1[i]; }
#pragma unroll
    for (int nf = 0; nf < 8; ++nf) {
      bf16x8 bfr = *(const bf16x8*)(wt + (size_t)(n0 + nf * 16 + nl) * 256 + ks * 32 + quad * 8);
      acc[nf] = __builtin_amdgcn_mfma_f32_16x16x32_bf16(af, bfr, acc[nf], 0, 0, 0);
    }
  }

  const int bq = m0 >> 12;          // batch (tile never crosses)
  const int s0 = m0 & 4095;         // seq offset of tile
  const int posl = wave * 16 + quad * 4;

  if (z == 2) {
    // LDS [col(128)][key(64)+pad8] pitch 72, b64 writes of 4 consecutive keys
    bf16* tv = (bf16*)smem;
#pragma unroll
    for (int nf = 0; nf < 8; ++nf) {
      const int col = nf * 16 + nl;
      bf16x4 o;
#pragma unroll
      for (int rr = 0; rr < 4; ++rr) o[rr] = (bf16)acc[nf][rr];
      *(bf16x4*)(tv + (size_t)col * 72 + posl) = o;
    }
    __syncthreads();
    const int h2 = tid >> 6, ln = tid & 63;
    const int d = ln & 31, shalf = ln >> 5;
    const int h = (n0 >> 5) + h2;
    bf16* vb = Vp + (size_t)(bq * 8 + h) * 131072 + (size_t)(s0 >> 5) * 1024 + d * 8;
#pragma unroll
    for (int it = 0; it < 4; ++it) {
      const int blk = it >> 1, sub = (it & 1) * 2 + shalf;
      const int K0 = (sub >> 1) * 16 + (sub & 1) * 4;
      const bf16* src = tv + (size_t)(h2 * 32 + d) * 72 + blk * 32 + K0;
      bf16x4 g0 = *(const bf16x4*)(src);
      bf16x4 g1 = *(const bf16x4*)(src + 8);
      bf16x8 o;
#pragma unroll
      for (int j = 0; j < 4; ++j) { o[j] = g0[j]; o[4 + j] = g1[j]; }
      *(bf16x8*)(vb + (size_t)blk * 1024 + sub * 256) = o;
    }
  } else {
    // LDS [pos(64)][col(128)+pad8] pitch 136, scalar writes, b128 reads
    bf16* tq = (bf16*)smem;
    const float scale = (z == 0) ? QSCALE : 1.0f;
#pragma unroll
    for (int nf = 0; nf < 8; ++nf) {
      const int col = nf * 16 + nl;
#pragma unroll
      for (int rr = 0; rr < 4; ++rr)
        tq[(size_t)(posl + rr) * 136 + col] = (bf16)(acc[nf][rr] * scale);
    }
    __syncthreads();
    bf16* Out = z == 0 ? Qp : Kp;
    const int h2 = tid >> 6, ln = tid & 63;   // ln = local pos
    const int h = (n0 >> 5) + h2;
    const int s = s0 + ln;
    bf16* ob = Out + (size_t)(bq * 8 + h) * 131072 + (size_t)(s >> 5) * 1024 + (s & 31) * 8;
#pragma unroll
    for (int sub = 0; sub < 4; ++sub) {
      bf16x8 o = *(const bf16x8*)(tq + (size_t)ln * 136 + h2 * 32 + sub * 8);
      *(bf16x8*)(ob + sub * 256) = o;
    }
  }
}

// ---------------- K3: attention — depth-4 K/mask prefetch, V loaded in-step ----------------
// Block: 64 q x full 4096 k. Wave w: q-subtile (w&1), k-half (w>>1).
// Latency analysis: STEP ~280 busy cy vs ~300-500 cy L2 load latency -> depth-2
// under-covers (the ~40% stall in R2's counters). Depth-4 on the K-side frags
// {ka0,ka1,m0} (9 regs each) gives ~3 STEPs (~850 cy) of cover; V is loaded at
// STEP start — it isn't consumed until after bias+QK-MFMA+exp2 (~200+ cy of
// intra-step self-cover). Register budget: 4x9 + acc 16 + qf 8 + ls 4 + addr
// ~= 116 peak, fits the pinned 128 (waves_per_eu(4,4); R6: without pinning the
// allocator picked 64 VGPR and spilled 1.4 GB/dispatch).
// Mask as C-operand bias (-inf) -> exp2 gives 0 for masked keys.
__global__ __launch_bounds__(256)
__attribute__((amdgpu_waves_per_eu(4, 4)))
void attn_kernel(
    const bf16* __restrict__ Qp, const bf16* __restrict__ Kp,
    const bf16* __restrict__ Vp, const uint* __restrict__ M2,
    bf16* __restrict__ Og) {
  const int id = blockIdx.x;                 // 1024 blocks = 4/CU, one round
  const int xcd = id & 7, slot = id >> 3;
  const int bh = xcd * 2 + (slot >> 6);      // 2 bh per XCD -> L2-resident K/V/mask
  const int q0 = (slot & 63) * 64;
  const int b = bh >> 3, h = bh & 7;
  const int tid = threadIdx.x, w = tid >> 6, lane = tid & 63;
  const int nl = lane & 31, half = lane >> 5;
  const int qsub = w & 1, kh = w >> 1;

  __shared__ float Ored[4][32][33];          // [wave][d][q] partial O
  __shared__ float Lsum[32][8];              // [q][w*2+half] partial lsum

  const size_t bhbase = (size_t)bh * 131072;
  const int so0 = half * 256 + nl * 8;
  const int so1 = 512 + half * 256 + nl * 8;

  bf16x8 qf0, qf1;
  {
    const bf16* qb = Qp + bhbase + (size_t)((q0 >> 5) + qsub) * 1024;
    qf0 = *(const bf16x8*)(qb + so0);
    qf1 = *(const bf16x8*)(qb + so1);
  }

  const bf16* Kw = Kp + bhbase + (size_t)kh * 65536;   // k-half base (64 blocks)
  const bf16* Vw = Vp + bhbase + (size_t)kh * 65536;
  const uint* Mw = M2 + (size_t)b * 524288 + (size_t)kh * 262144 + q0 + qsub * 32 + nl;

  f32x16 acc;
#pragma unroll
  for (int i = 0; i < 16; ++i) acc[i] = 0.f;
  f32x4 ls = {0.f, 0.f, 0.f, 0.f};           // 4 independent partial-sum chains

  struct Frag { bf16x8 ka0, ka1; uint m0; };  // K-side only: 9 VGPRs
  auto LOADK = [&](int kt) -> Frag {
    Frag f;
    const bf16* kc = Kw + (size_t)kt * 1024;
    f.ka0 = *(const bf16x8*)(kc + so0);
    f.ka1 = *(const bf16x8*)(kc + so1);
    f.m0 = Mw[(size_t)kt * 4096];
    return f;
  };

  auto STEP = [&](const Frag& f, int kt) {
    // V load issued FIRST: consumed only after bias+QK MFMA+exp2 (~200+ cy cover)
    const bf16* vc = Vw + (size_t)kt * 1024;
    const bf16x8 va0 = *(const bf16x8*)(vc + so0);
    const bf16x8 va1 = *(const bf16x8*)(vc + so1);

    // mask bits: key k5 = r + 8g + 4*half is bit (off + 4*half) of m0; bit=1 -> masked.
    const int mpos = (int)(f.m0 >> (4 * half));
    f32x16 bias;
#pragma unroll
    for (int g = 0; g < 4; ++g)
#pragma unroll
      for (int r = 0; r < 4; ++r) {
        const int i = g * 4 + r, off = r + 8 * g;
        const uint mb = (uint)__builtin_amdgcn_sbfe(mpos, off, 1);
        bias[i] = __uint_as_float(mb & 0xFF800000u);   // 0 or -inf
      }
    __builtin_amdgcn_s_setprio(1);
    f32x16 st = __builtin_amdgcn_mfma_f32_32x32x16_bf16(f.ka0, qf0, bias, 0, 0, 0);
    st = __builtin_amdgcn_mfma_f32_32x32x16_bf16(f.ka1, qf1, st, 0, 0, 0);
    __builtin_amdgcn_s_setprio(0);

    f32x16 pf;
#pragma unroll
    for (int g = 0; g < 4; ++g)
#pragma unroll
      for (int r = 0; r < 4; ++r) {
        const int i = g * 4 + r;
        const float e = __builtin_amdgcn_exp2f(st[i]);
        ls[g] += e;                                    // masked -> exp2(-inf)=0
        pf[i] = e;
      }

    const bf16x8 pb0 = __builtin_convertvector(
        __builtin_shufflevector(pf, pf, 0, 1, 2, 3, 4, 5, 6, 7), bf16x8);
    const bf16x8 pb1 = __builtin_convertvector(
        __builtin_shufflevector(pf, pf, 8, 9, 10, 11, 12, 13, 14, 15), bf16x8);

    __builtin_amdgcn_s_setprio(1);
    acc = __builtin_amdgcn_mfma_f32_32x32x16_bf16(va0, pb0, acc, 0, 0, 0);
    acc = __builtin_amdgcn_mfma_f32_32x32x16_bf16(va1, pb1, acc, 0, 0, 0);
    __builtin_amdgcn_s_setprio(0);
  };

  Frag f0 = LOADK(0), f1 = LOADK(1), f2 = LOADK(2), f3 = LOADK(3);
  for (int kt = 0; kt < 64; kt += 4) {
    // loose pacing barrier (raw: no waitcnt drain) keeps wave pairs within a
    // few tiles so shared K/V lines can hit L1/L2-near.
    if (kt) __builtin_amdgcn_s_barrier();
    STEP(f0, kt + 0); if (kt + 4 < 64) f0 = LOADK(kt + 4);
    STEP(f1, kt + 1); if (kt + 5 < 64) f1 = LOADK(kt + 5);
    STEP(f2, kt + 2); if (kt + 6 < 64) f2 = LOADK(kt + 6);
    STEP(f3, kt + 3); if (kt + 7 < 64) f3 = LOADK(kt + 7);
  }

  // ---- epilogue: reduce wave pairs {0,2},{1,3} (same q, two k-halves) ----
#pragma unroll
  for (int g = 0; g < 4; ++g)
#pragma unroll
    for (int r = 0; r < 4; ++r) {
      const int d = r + 8 * g + 4 * half, i = g * 4 + r;
      Ored[w][d][nl] = acc[i];
    }
  Lsum[nl][w * 2 + half] = (ls[0] + ls[1]) + (ls[2] + ls[3]);
  __syncthreads();
  {
    const int q = tid >> 2, d0 = (tid & 3) * 8;   // q 0..63, d0 0/8/16/24
    const int qq = q & 31, qs = q >> 5;
    const float s = (Lsum[qq][qs * 2] + Lsum[qq][qs * 2 + 1]) +
                    (Lsum[qq][(qs + 2) * 2] + Lsum[qq][(qs + 2) * 2 + 1]);
    const float rl = 1.0f / s;
    bf16x8 o;
#pragma unroll
    for (int dj = 0; dj < 8; ++dj) {
      const int d = d0 + dj;
      const float sum = Ored[qs][d][qq] + Ored[qs + 2][d][qq];
      o[dj] = (bf16)(sum * rl);
    }
    *(bf16x8*)(Og + ((size_t)(b * 4096 + q0 + q)) * 256 + h * 32 + d0) = o;
  }
}

// ---------------- K4: out = attn(bf16) @ w_out -> fp32, 64x64 tiles ----------------
__global__ __launch_bounds__(256, 2) void gemm_out(
    const bf16* __restrict__ A, const bf16* __restrict__ WTo, float* __restrict__ C) {
  const int m0 = blockIdx.x * 64, n0 = blockIdx.y * 64;
  const int tid = threadIdx.x, wave = tid >> 6, lane = tid & 63;
  const int nl = lane & 15, quad = lane >> 4;
  const int arow = m0 + wave * 16 + nl;

  f32x4 zero4 = {0.f, 0.f, 0.f, 0.f};
  f32x4 acc[4];
#pragma unroll
  for (int i = 0; i < 4; ++i) acc[i] = zero4;

  for (int ks = 0; ks < 8; ++ks) {
    bf16x8 af = *(const bf16x8*)(A + (size_t)arow * 256 + ks * 32 + quad * 8);
#pragma unroll
    for (int nf = 0; nf < 4; ++nf) {
      bf16x8 bfr = *(const bf16x8*)(WTo + (size_t)(n0 + nf * 16 + nl) * 256 + ks * 32 + quad * 8);
      acc[nf] = __builtin_amdgcn_mfma_f32_16x16x32_bf16(af, bfr, acc[nf], 0, 0, 0);
    }
  }
  const int Rbase = m0 + wave * 16 + quad * 4;
#pragma unroll
  for (int nf = 0; nf < 4; ++nf)
#pragma unroll
    for (int r = 0; r < 4; ++r)
      C[(size_t)(Rbase + r) * 256 + n0 + nf * 16 + nl] = acc[nf][r];
}

extern "C" void kernel_launch(void* const* d_in, const int* in_sizes, int n_in,
                              void* d_out, int out_size, void* d_ws, size_t ws_size,
                              hipStream_t stream) {
  const float* q  = (const float*)d_in[0];
  const float* k  = (const float*)d_in[1];
  const float* v  = (const float*)d_in[2];
  const int*  mask = (const int*)d_in[3];
  const float* wq = (const float*)d_in[4];
  const float* wk = (const float*)d_in[5];
  const float* wv = (const float*)d_in[6];
  const float* wo = (const float*)d_in[7];
  float* out = (float*)d_out;

  uint8_t* ws = (uint8_t*)d_ws;
  bf16* WT = (bf16*)ws;                               // 512 KB
  bf16* Qp = (bf16*)(ws + (512u << 10));              // frag-native 4 MB
  bf16* Kp = Qp + 2097152;                            // 4 MB
  bf16* Vp = Kp + 2097152;                            // 4 MB
  uint* Mb = (uint*)((uint8_t*)(Vp + 2097152));       // transposed packed mask 4 MB
  bf16* Ao = (bf16*)((uint8_t*)Mb + (4u << 20));      // attn bf16 [B,S,256] 4 MB

  transpose_w<<<dim3(4, 4, 4), 256, 0, stream>>>(wq, wk, wv, wo, WT);
  proj_pack<<<dim3(768 + 512), 256, 0, stream>>>(q, k, v, WT, Qp, Kp, Vp, mask, Mb);
  attn_kernel<<<dim3(1024), 256, 0, stream>>>(Qp, Kp, Vp, Mb, Ao);
  gemm_out<<<dim3(128, 4), 256, 0, stream>>>(Ao, WT + 3 * 65536, out);
}

// Round 13
// 305.190 us; speedup vs baseline: 1.3187x; 1.3187x over previous
//
#include <hip/hip_runtime.h>
#include <stdint.h>

typedef __bf16 bf16;
typedef __bf16 bf16x8 __attribute__((ext_vector_type(8)));
typedef __bf16 bf16x4 __attribute__((ext_vector_type(4)));
typedef float  f32x4  __attribute__((ext_vector_type(4)));
typedef float  f32x16 __attribute__((ext_vector_type(16)));
typedef float  float4v __attribute__((ext_vector_type(4)));
typedef int    int4v   __attribute__((ext_vector_type(4)));
typedef unsigned int uint;

// log2(e)/sqrt(32): folds softmax 1/sqrt(Dh) and e^x -> 2^x into Q scaling
#define QSCALE 0.25505003984214403f

// Fragment-native layout: [bh][blk(128)][sub(4)][lane(32)][8]
//  Q/K: (pos,d) -> blk=pos>>5, sub=d>>3, lane=pos&31, j=d&7
//  V  : (key,d) -> blk=key>>5, sub from key5 bits{4,2}, lane=d, j=g*4+(key5&3), g=(key5>>3)&1
// Mask M2: dword [(b*128+kdw)*4096 + q], bit k5 of kdw*32+k5 vs q.

// ---------------- K0: transpose weights -> bf16 WT[w][n][k] ----------------
__global__ __launch_bounds__(256) void transpose_w(
    const float* __restrict__ w0, const float* __restrict__ w1,
    const float* __restrict__ w2, const float* __restrict__ w3,
    bf16* __restrict__ WT) {
  const int wsel = blockIdx.z;
  const float* W = wsel == 0 ? w0 : wsel == 1 ? w1 : wsel == 2 ? w2 : w3;
  const int k0 = blockIdx.x * 64, n0 = blockIdx.y * 64;
  __shared__ __align__(16) bf16 t[64][72];
  const int tid = threadIdx.x;
  {
    const int kk = (tid >> 4) << 2;
    const int nn = (tid & 15) << 2;
#pragma unroll
    for (int r = 0; r < 4; ++r) {
      float4v a = *(const float4v*)(W + (size_t)(k0 + kk + r) * 256 + n0 + nn);
#pragma unroll
      for (int j = 0; j < 4; ++j) t[nn + j][kk + r] = (bf16)a[j];
    }
  }
  __syncthreads();
  {
    const int ni = tid >> 2;
    const int c  = (tid & 3) * 16;
    bf16x8 o0 = *(const bf16x8*)(&t[ni][c]);
    bf16x8 o1 = *(const bf16x8*)(&t[ni][c + 8]);
    bf16* dst = WT + (size_t)wsel * 65536 + (size_t)(n0 + ni) * 256 + k0 + c;
    *(bf16x8*)dst = o0;
    *(bf16x8*)(dst + 8) = o1;
  }
}

// ---------------- K1: fused proj (blocks 0..767) + pack_mask (768..1279) ----
// FROZEN: 5 structural variants all land at 77-79us (coalescing, ILP depth,
// split/fused, register budget). The mask read stream runs at ~1.4 TB/s on
// this machine regardless — treated as a platform ceiling for this pattern.
__global__ __launch_bounds__(256)
__attribute__((amdgpu_waves_per_eu(4, 4)))
void proj_pack(
    const float* __restrict__ xq, const float* __restrict__ xk, const float* __restrict__ xv,
    const bf16* __restrict__ WT,
    bf16* __restrict__ Qp, bf16* __restrict__ Kp, bf16* __restrict__ Vp,
    const int* __restrict__ mask, uint* __restrict__ M2) {
  __shared__ __align__(16) unsigned char smem[18432];
  const int tid = threadIdx.x;

  if (blockIdx.x >= 768) {
    // ---- pack_mask: 64 q x 1024 k tile, fully-coalesced reads ----
    uint* lds32 = (uint*)smem;                    // [64][65] u32, pitch 65 (conflict-free)
    const int pid = blockIdx.x - 768;             // 512 blocks
    const int bb = pid >> 8;                      // batch
    const int qt = (pid >> 2) & 63, kc = pid & 3;
    const int q0 = qt * 64;
    const int w = tid >> 6, l = tid & 63;
#pragma unroll 4
    for (int r = 0; r < 16; ++r) {
      const int row = w * 16 + r;
      const size_t rowbase = ((size_t)(bb * 4096 + q0 + row)) * 4096 + kc * 1024;
      uint u = 0;
#pragma unroll
      for (int i = 0; i < 4; ++i) {
        int4v m = *(const int4v*)(mask + rowbase + i * 256 + l * 4);
        uint nib = (m[0] != 0 ? 1u : 0u) | (m[1] != 0 ? 2u : 0u) |
                   (m[2] != 0 ? 4u : 0u) | (m[3] != 0 ? 8u : 0u);
        u |= nib << (i * 8);
      }
      lds32[row * 65 + l] = u;
    }
    __syncthreads();
    {
      const int q = tid & 63, kg = tid >> 6;
      const uint* lrow = lds32 + q * 65;
      const int sh = kg * 8;
      uint* o = M2 + ((size_t)(bb * 128 + kc * 32 + kg * 8)) * 4096 + q0 + q;
#pragma unroll
      for (int j = 0; j < 8; ++j) {
        uint d = 0;
#pragma unroll
        for (int jj = 0; jj < 8; ++jj) {
          const uint wv = lrow[j * 8 + jj];
          d |= ((wv >> sh) & 0xFu) << (jj * 4);
        }
        o[(size_t)j * 4096] = d;
      }
    }
    return;
  }

  // ---- proj: 64 pos x 128 cols tile, epilogue through LDS for coalesced stores ----
  const int z = blockIdx.x >> 8;
  const int r8 = blockIdx.x & 255;
  const int m0 = (r8 >> 1) * 64, n0 = (r8 & 1) * 128;
  const float* X = z == 0 ? xq : (z == 1 ? xk : xv);
  const bf16* wt = WT + (size_t)z * 65536;
  const int wave = tid >> 6, lane = tid & 63;
  const int nl = lane & 15, quad = lane >> 4;
  const int arow = m0 + wave * 16 + nl;
  const float* xrow = X + (size_t)arow * 256;

  f32x4 zero4 = {0.f, 0.f, 0.f, 0.f};
  f32x4 acc[8];
#pragma unroll
  for (int i = 0; i < 8; ++i) acc[i] = zero4;

#pragma unroll
  for (int ks = 0; ks < 8; ++ks) {
    float4v a0 = *(const float4v*)(xrow + ks * 32 + quad * 8);
    float4v a1 = *(const float4v*)(xrow + ks * 32 + quad * 8 + 4);
    bf16x8 af;
#pragma unroll
    for (int i = 0; i < 4; ++i) { af[i] = (bf16)a0[i]; af[4 + i] = (bf16)a1[i]; }
#pragma unroll
    for (int nf = 0; nf < 8; ++nf) {
      bf16x8 bfr = *(const bf16x8*)(wt + (size_t)(n0 + nf * 16 + nl) * 256 + ks * 32 + quad * 8);
      acc[nf] = __builtin_amdgcn_mfma_f32_16x16x32_bf16(af, bfr, acc[nf], 0, 0, 0);
    }
  }

  const int bq = m0 >> 12;          // batch (tile never crosses)
  const int s0 = m0 & 4095;         // seq offset of tile
  const int posl = wave * 16 + quad * 4;

  if (z == 2) {
    // LDS [col(128)][key(64)+pad8] pitch 72, b64 writes of 4 consecutive keys
    bf16* tv = (bf16*)smem;
#pragma unroll
    for (int nf = 0; nf < 8; ++nf) {
      const int col = nf * 16 + nl;
      bf16x4 o;
#pragma unroll
      for (int rr = 0; rr < 4; ++rr) o[rr] = (bf16)acc[nf][rr];
      *(bf16x4*)(tv + (size_t)col * 72 + posl) = o;
    }
    __syncthreads();
    const int h2 = tid >> 6, ln = tid & 63;
    const int d = ln & 31, shalf = ln >> 5;
    const int h = (n0 >> 5) + h2;
    bf16* vb = Vp + (size_t)(bq * 8 + h) * 131072 + (size_t)(s0 >> 5) * 1024 + d * 8;
#pragma unroll
    for (int it = 0; it < 4; ++it) {
      const int blk = it >> 1, sub = (it & 1) * 2 + shalf;
      const int K0 = (sub >> 1) * 16 + (sub & 1) * 4;
      const bf16* src = tv + (size_t)(h2 * 32 + d) * 72 + blk * 32 + K0;
      bf16x4 g0 = *(const bf16x4*)(src);
      bf16x4 g1 = *(const bf16x4*)(src + 8);
      bf16x8 o;
#pragma unroll
      for (int j = 0; j < 4; ++j) { o[j] = g0[j]; o[4 + j] = g1[j]; }
      *(bf16x8*)(vb + (size_t)blk * 1024 + sub * 256) = o;
    }
  } else {
    // LDS [pos(64)][col(128)+pad8] pitch 136, scalar writes, b128 reads
    bf16* tq = (bf16*)smem;
    const float scale = (z == 0) ? QSCALE : 1.0f;
#pragma unroll
    for (int nf = 0; nf < 8; ++nf) {
      const int col = nf * 16 + nl;
#pragma unroll
      for (int rr = 0; rr < 4; ++rr)
        tq[(size_t)(posl + rr) * 136 + col] = (bf16)(acc[nf][rr] * scale);
    }
    __syncthreads();
    bf16* Out = z == 0 ? Qp : Kp;
    const int h2 = tid >> 6, ln = tid & 63;   // ln = local pos
    const int h = (n0 >> 5) + h2;
    const int s = s0 + ln;
    bf16* ob = Out + (size_t)(bq * 8 + h) * 131072 + (size_t)(s >> 5) * 1024 + (s & 31) * 8;
#pragma unroll
    for (int sub = 0; sub < 4; ++sub) {
      bf16x8 o = *(const bf16x8*)(tq + (size_t)ln * 136 + h2 * 32 + sub * 8);
      *(bf16x8*)(ob + sub * 256) = o;
    }
  }
}

// ---------------- K3: attention — depth-2 K-side prefetch, V loaded in-step ----------------
// Block: 64 q x full 4096 k. Wave w: q-subtile (w&1), k-half (w>>1).
// HARD CONSTRAINT (R6+R12, twice-confirmed): the allocator pins this kernel
// at a 64-VGPR allocation regardless of waves_per_eu/launch_bounds hints —
// anything over ~64 live regs SPILLS (R12: 502 MB scratch writes, 165us).
// Design for <=64 live: K-side depth-2 frags {ka0,ka1,m0} = 9 regs each
// (vs R10's 17 with V), V loaded at STEP start — consumed only after
// bias+QK-MFMA+exp2 (~200 cy intra-step self-cover). Live set ~56 < 64.
// Mask as C-operand bias (-inf) -> exp2 gives 0 for masked keys.
__global__ __launch_bounds__(256)
__attribute__((amdgpu_waves_per_eu(4, 4)))
void attn_kernel(
    const bf16* __restrict__ Qp, const bf16* __restrict__ Kp,
    const bf16* __restrict__ Vp, const uint* __restrict__ M2,
    bf16* __restrict__ Og) {
  const int id = blockIdx.x;                 // 1024 blocks = 4/CU, one round
  const int xcd = id & 7, slot = id >> 3;
  const int bh = xcd * 2 + (slot >> 6);      // 2 bh per XCD -> L2-resident K/V/mask
  const int q0 = (slot & 63) * 64;
  const int b = bh >> 3, h = bh & 7;
  const int tid = threadIdx.x, w = tid >> 6, lane = tid & 63;
  const int nl = lane & 31, half = lane >> 5;
  const int qsub = w & 1, kh = w >> 1;

  __shared__ float Ored[4][32][33];          // [wave][d][q] partial O
  __shared__ float Lsum[32][8];              // [q][w*2+half] partial lsum

  const size_t bhbase = (size_t)bh * 131072;
  const int so0 = half * 256 + nl * 8;
  const int so1 = 512 + half * 256 + nl * 8;

  bf16x8 qf0, qf1;
  {
    const bf16* qb = Qp + bhbase + (size_t)((q0 >> 5) + qsub) * 1024;
    qf0 = *(const bf16x8*)(qb + so0);
    qf1 = *(const bf16x8*)(qb + so1);
  }

  const bf16* Kw = Kp + bhbase + (size_t)kh * 65536;   // k-half base (64 blocks)
  const bf16* Vw = Vp + bhbase + (size_t)kh * 65536;
  const uint* Mw = M2 + (size_t)b * 524288 + (size_t)kh * 262144 + q0 + qsub * 32 + nl;

  f32x16 acc;
#pragma unroll
  for (int i = 0; i < 16; ++i) acc[i] = 0.f;
  f32x4 ls = {0.f, 0.f, 0.f, 0.f};           // 4 independent partial-sum chains

  struct Frag { bf16x8 ka0, ka1; uint m0; };  // K-side only: 9 VGPRs
  auto LOADK = [&](int kt) -> Frag {
    Frag f;
    const bf16* kc = Kw + (size_t)kt * 1024;
    f.ka0 = *(const bf16x8*)(kc + so0);
    f.ka1 = *(const bf16x8*)(kc + so1);
    f.m0 = Mw[(size_t)kt * 4096];
    return f;
  };

  auto STEP = [&](const Frag& f, int kt) {
    // V load issued FIRST: consumed only after bias+QK MFMA+exp2 (~200+ cy cover)
    const bf16* vc = Vw + (size_t)kt * 1024;
    const bf16x8 va0 = *(const bf16x8*)(vc + so0);
    const bf16x8 va1 = *(const bf16x8*)(vc + so1);

    // mask bits: key k5 = r + 8g + 4*half is bit (off + 4*half) of m0; bit=1 -> masked.
    const int mpos = (int)(f.m0 >> (4 * half));
    f32x16 bias;
#pragma unroll
    for (int g = 0; g < 4; ++g)
#pragma unroll
      for (int r = 0; r < 4; ++r) {
        const int i = g * 4 + r, off = r + 8 * g;
        const uint mb = (uint)__builtin_amdgcn_sbfe(mpos, off, 1);
        bias[i] = __uint_as_float(mb & 0xFF800000u);   // 0 or -inf
      }
    __builtin_amdgcn_s_setprio(1);
    f32x16 st = __builtin_amdgcn_mfma_f32_32x32x16_bf16(f.ka0, qf0, bias, 0, 0, 0);
    st = __builtin_amdgcn_mfma_f32_32x32x16_bf16(f.ka1, qf1, st, 0, 0, 0);
    __builtin_amdgcn_s_setprio(0);

    f32x16 pf;
#pragma unroll
    for (int g = 0; g < 4; ++g)
#pragma unroll
      for (int r = 0; r < 4; ++r) {
        const int i = g * 4 + r;
        const float e = __builtin_amdgcn_exp2f(st[i]);
        ls[g] += e;                                    // masked -> exp2(-inf)=0
        pf[i] = e;
      }

    const bf16x8 pb0 = __builtin_convertvector(
        __builtin_shufflevector(pf, pf, 0, 1, 2, 3, 4, 5, 6, 7), bf16x8);
    const bf16x8 pb1 = __builtin_convertvector(
        __builtin_shufflevector(pf, pf, 8, 9, 10, 11, 12, 13, 14, 15), bf16x8);

    __builtin_amdgcn_s_setprio(1);
    acc = __builtin_amdgcn_mfma_f32_32x32x16_bf16(va0, pb0, acc, 0, 0, 0);
    acc = __builtin_amdgcn_mfma_f32_32x32x16_bf16(va1, pb1, acc, 0, 0, 0);
    __builtin_amdgcn_s_setprio(0);
  };

  Frag fa = LOADK(0), fb;
  for (int kt = 0; kt < 64; kt += 2) {
    // loose pacing barrier: keeps wave pairs within ~4 tiles so shared K/V
    // lines survive in L1/L2-near. Raw s_barrier: NO waitcnt drain.
    if (kt && !(kt & 3)) __builtin_amdgcn_s_barrier();
    fb = LOADK(kt + 1);
    STEP(fa, kt);
    if (kt + 2 < 64) fa = LOADK(kt + 2);
    STEP(fb, kt + 1);
  }

  // ---- epilogue: reduce wave pairs {0,2},{1,3} (same q, two k-halves) ----
#pragma unroll
  for (int g = 0; g < 4; ++g)
#pragma unroll
    for (int r = 0; r < 4; ++r) {
      const int d = r + 8 * g + 4 * half, i = g * 4 + r;
      Ored[w][d][nl] = acc[i];
    }
  Lsum[nl][w * 2 + half] = (ls[0] + ls[1]) + (ls[2] + ls[3]);
  __syncthreads();
  {
    const int q = tid >> 2, d0 = (tid & 3) * 8;   // q 0..63, d0 0/8/16/24
    const int qq = q & 31, qs = q >> 5;
    const float s = (Lsum[qq][qs * 2] + Lsum[qq][qs * 2 + 1]) +
                    (Lsum[qq][(qs + 2) * 2] + Lsum[qq][(qs + 2) * 2 + 1]);
    const float rl = 1.0f / s;
    bf16x8 o;
#pragma unroll
    for (int dj = 0; dj < 8; ++dj) {
      const int d = d0 + dj;
      const float sum = Ored[qs][d][qq] + Ored[qs + 2][d][qq];
      o[dj] = (bf16)(sum * rl);
    }
    *(bf16x8*)(Og + ((size_t)(b * 4096 + q0 + q)) * 256 + h * 32 + d0) = o;
  }
}

// ---------------- K4: out = attn(bf16) @ w_out -> fp32, 64x64 tiles ----------------
__global__ __launch_bounds__(256, 2) void gemm_out(
    const bf16* __restrict__ A, const bf16* __restrict__ WTo, float* __restrict__ C) {
  const int m0 = blockIdx.x * 64, n0 = blockIdx.y * 64;
  const int tid = threadIdx.x, wave = tid >> 6, lane = tid & 63;
  const int nl = lane & 15, quad = lane >> 4;
  const int arow = m0 + wave * 16 + nl;

  f32x4 zero4 = {0.f, 0.f, 0.f, 0.f};
  f32x4 acc[4];
#pragma unroll
  for (int i = 0; i < 4; ++i) acc[i] = zero4;

  for (int ks = 0; ks < 8; ++ks) {
    bf16x8 af = *(const bf16x8*)(A + (size_t)arow * 256 + ks * 32 + quad * 8);
#pragma unroll
    for (int nf = 0; nf < 4; ++nf) {
      bf16x8 bfr = *(const bf16x8*)(WTo + (size_t)(n0 + nf * 16 + nl) * 256 + ks * 32 + quad * 8);
      acc[nf] = __builtin_amdgcn_mfma_f32_16x16x32_bf16(af, bfr, acc[nf], 0, 0, 0);
    }
  }
  const int Rbase = m0 + wave * 16 + quad * 4;
#pragma unroll
  for (int nf = 0; nf < 4; ++nf)
#pragma unroll
    for (int r = 0; r < 4; ++r)
      C[(size_t)(Rbase + r) * 256 + n0 + nf * 16 + nl] = acc[nf][r];
}

extern "C" void kernel_launch(void* const* d_in, const int* in_sizes, int n_in,
                              void* d_out, int out_size, void* d_ws, size_t ws_size,
                              hipStream_t stream) {
  const float* q  = (const float*)d_in[0];
  const float* k  = (const float*)d_in[1];
  const float* v  = (const float*)d_in[2];
  const int*  mask = (const int*)d_in[3];
  const float* wq = (const float*)d_in[4];
  const float* wk = (const float*)d_in[5];
  const float* wv = (const float*)d_in[6];
  const float* wo = (const float*)d_in[7];
  float* out = (float*)d_out;

  uint8_t* ws = (uint8_t*)d_ws;
  bf16* WT = (bf16*)ws;                               // 512 KB
  bf16* Qp = (bf16*)(ws + (512u << 10));              // frag-native 4 MB
  bf16* Kp = Qp + 2097152;                            // 4 MB
  bf16* Vp = Kp + 2097152;                            // 4 MB
  uint* Mb = (uint*)((uint8_t*)(Vp + 2097152));       // transposed packed mask 4 MB
  bf16* Ao = (bf16*)((uint8_t*)Mb + (4u << 20));      // attn bf16 [B,S,256] 4 MB

  transpose_w<<<dim3(4, 4, 4), 256, 0, stream>>>(wq, wk, wv, wo, WT);
  proj_pack<<<dim3(768 + 512), 256, 0, stream>>>(q, k, v, WT, Qp, Kp, Vp, mask, Mb);
  attn_kernel<<<dim3(1024), 256, 0, stream>>>(Qp, Kp, Vp, Mb, Ao);
  gemm_out<<<dim3(128, 4), 256, 0, stream>>>(Ao, WT + 3 * 65536, out);
}